// Round 1
// baseline (92.611 us; speedup 1.0000x reference)
//
#include <hip/hip_runtime.h>

// LindbladLoss: reference scan collapses to ordered product of 2x2 complex
// matrices B_t = scale*(I - i*dt*A_t), A_t = [[d/2, ox-i*oy],[ox+i*oy, -d/2]].
// fidelity = |P00|^2 / 4 where P = B_{N-1} * ... * B_0.
// total_loss = (1 - fidelity) + 0.01 * mean((pulses[1:]-pulses[:-1])^2).

#define N_STEPS 2097152
#define K1_BLOCKS 1024
#define K1_THREADS 256
#define STEPS_PER_THREAD (N_STEPS / (K1_BLOCKS * K1_THREADS)) // = 8

struct C2 { double re, im; };

__device__ inline C2 cmul(C2 a, C2 b) {
    C2 r; r.re = a.re * b.re - a.im * b.im; r.im = a.re * b.im + a.im * b.re; return r;
}
__device__ inline C2 cadd(C2 a, C2 b) { C2 r; r.re = a.re + b.re; r.im = a.im + b.im; return r; }

// Multiply 2x2 complex matrices: out = L * R (L = later steps, left factor).
__device__ inline void mat_mul(const double* L, const double* R, double* out) {
    C2 l00 = {L[0], L[1]}, l01 = {L[2], L[3]}, l10 = {L[4], L[5]}, l11 = {L[6], L[7]};
    C2 r00 = {R[0], R[1]}, r01 = {R[2], R[3]}, r10 = {R[4], R[5]}, r11 = {R[6], R[7]};
    C2 n00 = cadd(cmul(l00, r00), cmul(l01, r10));
    C2 n01 = cadd(cmul(l00, r01), cmul(l01, r11));
    C2 n10 = cadd(cmul(l10, r00), cmul(l11, r10));
    C2 n11 = cadd(cmul(l10, r01), cmul(l11, r11));
    out[0] = n00.re; out[1] = n00.im; out[2] = n01.re; out[3] = n01.im;
    out[4] = n10.re; out[5] = n10.im; out[6] = n11.re; out[7] = n11.im;
}

__global__ __launch_bounds__(K1_THREADS) void lindblad_partial_kernel(
    const float* __restrict__ pulses, const float* __restrict__ dt_ptr,
    double* __restrict__ ws) {
    const int tid = threadIdx.x;
    const int gid = blockIdx.x * K1_THREADS + tid;
    const long s0 = (long)gid * STEPS_PER_THREAD;

    // Mimic the reference's fp32 evaluation of p and scale, then go fp64.
    const float dtf = dt_ptr[0];
    const float pf = (0.01f * dtf) * 1e9f;
    const double s = (double)(1.0f - pf);
    const double dt = (double)dtf;

    C2 p00 = {1.0, 0.0}, p01 = {0.0, 0.0}, p10 = {0.0, 0.0}, p11 = {1.0, 0.0};
    double reg = 0.0;

    for (int k = 0; k < STEPS_PER_THREAD; ++k) {
        const long t = s0 + k;
        const float ox = pulses[3 * t + 0];
        const float oy = pulses[3 * t + 1];
        const float dl = pulses[3 * t + 2];

        // B = s * [[1 - 0.5*i*dt*dl,  dt*(-oy - i*ox)],
        //          [dt*(oy - i*ox),   1 + 0.5*i*dt*dl]]
        const double sdt = s * dt;
        C2 b00 = { s,                 -0.5 * sdt * (double)dl };
        C2 b01 = { -sdt * (double)oy, -sdt * (double)ox };
        C2 b10 = {  sdt * (double)oy, -sdt * (double)ox };
        C2 b11 = { s,                  0.5 * sdt * (double)dl };

        // P = B * P
        C2 n00 = cadd(cmul(b00, p00), cmul(b01, p10));
        C2 n01 = cadd(cmul(b00, p01), cmul(b01, p11));
        C2 n10 = cadd(cmul(b10, p00), cmul(b11, p10));
        C2 n11 = cadd(cmul(b10, p01), cmul(b11, p11));
        p00 = n00; p01 = n01; p10 = n10; p11 = n11;

        // regularization: diff with next step (valid for t < N-1)
        if (t < N_STEPS - 1) {
            const float nx = pulses[3 * t + 3];
            const float ny = pulses[3 * t + 4];
            const float nz = pulses[3 * t + 5];
            const double dx = (double)nx - (double)ox;
            const double dy = (double)ny - (double)oy;
            const double dz = (double)nz - (double)dl;
            reg += dx * dx + dy * dy + dz * dz;
        }
    }

    __shared__ double sm[K1_THREADS][8];
    __shared__ double sr[K1_THREADS];
    sm[tid][0] = p00.re; sm[tid][1] = p00.im;
    sm[tid][2] = p01.re; sm[tid][3] = p01.im;
    sm[tid][4] = p10.re; sm[tid][5] = p10.im;
    sm[tid][6] = p11.re; sm[tid][7] = p11.im;
    sr[tid] = reg;

    // Ordered tree reduction: higher tid = later steps = left factor.
    for (int off = 1; off < K1_THREADS; off <<= 1) {
        __syncthreads();
        if ((tid & (2 * off - 1)) == 0) {
            double tmp[8];
            mat_mul(sm[tid + off], sm[tid], tmp);
            #pragma unroll
            for (int j = 0; j < 8; ++j) sm[tid][j] = tmp[j];
            sr[tid] += sr[tid + off];
        }
    }

    if (tid == 0) {
        double* out = ws + (size_t)blockIdx.x * 9;
        #pragma unroll
        for (int j = 0; j < 8; ++j) out[j] = sm[0][j];
        out[8] = sr[0];
    }
}

#define K2_THREADS 256
#define PARTIALS_PER_THREAD (K1_BLOCKS / K2_THREADS) // = 4

__global__ __launch_bounds__(K2_THREADS) void lindblad_final_kernel(
    const double* __restrict__ ws, float* __restrict__ out) {
    const int tid = threadIdx.x;

    // Each thread combines 4 consecutive block-partials in order.
    double acc[8] = {1.0, 0.0, 0.0, 0.0, 0.0, 0.0, 1.0, 0.0}; // identity
    double reg = 0.0;
    #pragma unroll
    for (int j = 0; j < PARTIALS_PER_THREAD; ++j) {
        const double* p = ws + (size_t)(tid * PARTIALS_PER_THREAD + j) * 9;
        double L[8];
        #pragma unroll
        for (int q = 0; q < 8; ++q) L[q] = p[q];
        double tmp[8];
        mat_mul(L, acc, tmp);  // later partial on the left
        #pragma unroll
        for (int q = 0; q < 8; ++q) acc[q] = tmp[q];
        reg += p[8];
    }

    __shared__ double sm[K2_THREADS][8];
    __shared__ double sr[K2_THREADS];
    #pragma unroll
    for (int j = 0; j < 8; ++j) sm[tid][j] = acc[j];
    sr[tid] = reg;

    for (int off = 1; off < K2_THREADS; off <<= 1) {
        __syncthreads();
        if ((tid & (2 * off - 1)) == 0) {
            double tmp[8];
            mat_mul(sm[tid + off], sm[tid], tmp);
            #pragma unroll
            for (int j = 0; j < 8; ++j) sm[tid][j] = tmp[j];
            sr[tid] += sr[tid + off];
        }
    }

    if (tid == 0) {
        const double p00r = sm[0][0], p00i = sm[0][1];
        // tr(CNOT^H U) = 2*P00; overlap = |2*P00|^2; fidelity = overlap/16.
        const double tr_re = 2.0 * p00r, tr_im = 2.0 * p00i;
        const double fid = (tr_re * tr_re + tr_im * tr_im) / 16.0;
        const double reg_mean = sr[0] / (3.0 * (double)(N_STEPS - 1));
        const double total = (1.0 - fid) + 0.01 * reg_mean;
        out[0] = (float)total;
        out[1] = (float)fid;
    }
}

extern "C" void kernel_launch(void* const* d_in, const int* in_sizes, int n_in,
                              void* d_out, int out_size, void* d_ws, size_t ws_size,
                              hipStream_t stream) {
    const float* pulses = (const float*)d_in[0];
    const float* dt_ptr = (const float*)d_in[1];
    float* out = (float*)d_out;
    double* ws = (double*)d_ws;

    lindblad_partial_kernel<<<K1_BLOCKS, K1_THREADS, 0, stream>>>(pulses, dt_ptr, ws);
    lindblad_final_kernel<<<1, K2_THREADS, 0, stream>>>(ws, out);
}

// Round 2
// 80.039 us; speedup vs baseline: 1.1571x; 1.1571x over previous
//
#include <hip/hip_runtime.h>

// LindbladLoss: reference scan collapses to ordered product of 2x2 complex
// matrices B_t = scale*(I - i*dt*A_t), A_t = [[d/2, ox-i*oy],[ox+i*oy, -d/2]].
// fidelity = |P00|^2 / 4 where P = B_{N-1} * ... * B_0.
// total_loss = (1 - fidelity) + 0.01 * mean((pulses[1:]-pulses[:-1])^2).
//
// R2: float4 vectorized pulse loads (6 per thread, 16B/lane), ordered
// wave-shuffle butterfly reduction instead of LDS tree.

#define N_STEPS 2097152
#define K1_BLOCKS 1024
#define K1_THREADS 256
#define TOTAL_THREADS (K1_BLOCKS * K1_THREADS)
#define STEPS_PER_THREAD (N_STEPS / TOTAL_THREADS) // = 8

struct C2 { double re, im; };

__device__ inline C2 cmul(C2 a, C2 b) {
    C2 r; r.re = a.re * b.re - a.im * b.im; r.im = a.re * b.im + a.im * b.re; return r;
}
__device__ inline C2 cadd(C2 a, C2 b) { C2 r; r.re = a.re + b.re; r.im = a.im + b.im; return r; }

// out = L * R (L = later steps, left factor). 8 doubles per matrix:
// [00re,00im,01re,01im,10re,10im,11re,11im]
__device__ inline void mat_mul(const double* L, const double* R, double* out) {
    C2 l00 = {L[0], L[1]}, l01 = {L[2], L[3]}, l10 = {L[4], L[5]}, l11 = {L[6], L[7]};
    C2 r00 = {R[0], R[1]}, r01 = {R[2], R[3]}, r10 = {R[4], R[5]}, r11 = {R[6], R[7]};
    C2 n00 = cadd(cmul(l00, r00), cmul(l01, r10));
    C2 n01 = cadd(cmul(l00, r01), cmul(l01, r11));
    C2 n10 = cadd(cmul(l10, r00), cmul(l11, r10));
    C2 n11 = cadd(cmul(l10, r01), cmul(l11, r11));
    out[0] = n00.re; out[1] = n00.im; out[2] = n01.re; out[3] = n01.im;
    out[4] = n10.re; out[5] = n10.im; out[6] = n11.re; out[7] = n11.im;
}

// Ordered butterfly over a full wave: lane with bit `off` set holds the LATER
// chunk (left factor). After 6 rounds every lane holds the wave's product.
__device__ inline void wave_reduce_mat(double* m, double& reg) {
    const int lane = threadIdx.x & 63;
    #pragma unroll
    for (int off = 1; off < 64; off <<= 1) {
        double other[8];
        #pragma unroll
        for (int j = 0; j < 8; ++j) other[j] = __shfl_xor(m[j], off, 64);
        double tmp[8];
        if (lane & off) mat_mul(m, other, tmp);   // I'm later: L = mine
        else            mat_mul(other, m, tmp);   // partner later: L = other
        #pragma unroll
        for (int j = 0; j < 8; ++j) m[j] = tmp[j];
        reg += __shfl_xor(reg, off, 64);
    }
}

__global__ __launch_bounds__(K1_THREADS) void lindblad_partial_kernel(
    const float* __restrict__ pulses, const float* __restrict__ dt_ptr,
    double* __restrict__ ws) {
    const int tid = threadIdx.x;
    const int gid = blockIdx.x * K1_THREADS + tid;

    const float dtf = dt_ptr[0];
    const float pf = (0.01f * dtf) * 1e9f;   // mimic reference fp32 rounding
    const double s = (double)(1.0f - pf);
    const double dt = (double)dtf;
    const double sdt = s * dt;

    // Load this thread's 24 floats (8 steps x 3) as 6 float4s. base = 96*gid bytes.
    float arr[24];
    {
        const float4* p4 = (const float4*)(pulses + (size_t)gid * 24);
        #pragma unroll
        for (int j = 0; j < 6; ++j) {
            float4 v = p4[j];
            arr[4 * j + 0] = v.x; arr[4 * j + 1] = v.y;
            arr[4 * j + 2] = v.z; arr[4 * j + 3] = v.w;
        }
    }
    // Boundary: first 3 floats of the next chunk (for the last diff).
    float nx = 0.f, ny = 0.f, nz = 0.f;
    const bool has_next = (gid < TOTAL_THREADS - 1);
    if (has_next) {
        const float* nxt = pulses + (size_t)(gid + 1) * 24;
        nx = nxt[0]; ny = nxt[1]; nz = nxt[2];
    }

    C2 p00 = {1.0, 0.0}, p01 = {0.0, 0.0}, p10 = {0.0, 0.0}, p11 = {1.0, 0.0};
    double reg = 0.0;

    #pragma unroll
    for (int k = 0; k < STEPS_PER_THREAD; ++k) {
        const double ox = (double)arr[3 * k + 0];
        const double oy = (double)arr[3 * k + 1];
        const double dl = (double)arr[3 * k + 2];

        // B = s * [[1 - 0.5*i*dt*dl,  dt*(-oy - i*ox)],
        //          [dt*(oy - i*ox),   1 + 0.5*i*dt*dl]]
        C2 b00 = { s,         -0.5 * sdt * dl };
        C2 b01 = { -sdt * oy, -sdt * ox };
        C2 b10 = {  sdt * oy, -sdt * ox };
        C2 b11 = { s,          0.5 * sdt * dl };

        C2 n00 = cadd(cmul(b00, p00), cmul(b01, p10));
        C2 n01 = cadd(cmul(b00, p01), cmul(b01, p11));
        C2 n10 = cadd(cmul(b10, p00), cmul(b11, p10));
        C2 n11 = cadd(cmul(b10, p01), cmul(b11, p11));
        p00 = n00; p01 = n01; p10 = n10; p11 = n11;

        // diff t -> t+1
        double dx, dy, dz;
        if (k < STEPS_PER_THREAD - 1) {
            dx = (double)arr[3 * k + 3] - ox;
            dy = (double)arr[3 * k + 4] - oy;
            dz = (double)arr[3 * k + 5] - dl;
            reg += dx * dx + dy * dy + dz * dz;
        } else if (has_next) {
            dx = (double)nx - ox; dy = (double)ny - oy; dz = (double)nz - dl;
            reg += dx * dx + dy * dy + dz * dz;
        }
    }

    double m[8] = {p00.re, p00.im, p01.re, p01.im, p10.re, p10.im, p11.re, p11.im};
    wave_reduce_mat(m, reg);

    // Combine the block's 4 waves in order (wave 3 latest = left-most).
    __shared__ double wm[4][8];
    __shared__ double wr[4];
    const int wave = tid >> 6;
    if ((tid & 63) == 0) {
        #pragma unroll
        for (int j = 0; j < 8; ++j) wm[wave][j] = m[j];
        wr[wave] = reg;
    }
    __syncthreads();
    if (tid == 0) {
        double acc[8], tmp[8];
        #pragma unroll
        for (int j = 0; j < 8; ++j) acc[j] = wm[0][j];
        double r = wr[0];
        #pragma unroll
        for (int w = 1; w < 4; ++w) {
            mat_mul(wm[w], acc, tmp);
            #pragma unroll
            for (int j = 0; j < 8; ++j) acc[j] = tmp[j];
            r += wr[w];
        }
        double* out = ws + (size_t)blockIdx.x * 9;
        #pragma unroll
        for (int j = 0; j < 8; ++j) out[j] = acc[j];
        out[8] = r;
    }
}

#define K2_THREADS 256
#define PARTIALS_PER_THREAD (K1_BLOCKS / K2_THREADS) // = 4

__global__ __launch_bounds__(K2_THREADS) void lindblad_final_kernel(
    const double* __restrict__ ws, float* __restrict__ out) {
    const int tid = threadIdx.x;

    // Serially combine 4 consecutive partials (later partial on the left).
    double acc[8] = {1.0, 0.0, 0.0, 0.0, 0.0, 0.0, 1.0, 0.0};
    double reg = 0.0;
    #pragma unroll
    for (int j = 0; j < PARTIALS_PER_THREAD; ++j) {
        const double* p = ws + (size_t)(tid * PARTIALS_PER_THREAD + j) * 9;
        double L[8], tmp[8];
        #pragma unroll
        for (int q = 0; q < 8; ++q) L[q] = p[q];
        mat_mul(L, acc, tmp);
        #pragma unroll
        for (int q = 0; q < 8; ++q) acc[q] = tmp[q];
        reg += p[8];
    }

    wave_reduce_mat(acc, reg);

    __shared__ double wm[4][8];
    __shared__ double wr[4];
    const int wave = tid >> 6;
    if ((tid & 63) == 0) {
        #pragma unroll
        for (int j = 0; j < 8; ++j) wm[wave][j] = acc[j];
        wr[wave] = reg;
    }
    __syncthreads();
    if (tid == 0) {
        double fin[8], tmp[8];
        #pragma unroll
        for (int j = 0; j < 8; ++j) fin[j] = wm[0][j];
        double r = wr[0];
        #pragma unroll
        for (int w = 1; w < 4; ++w) {
            mat_mul(wm[w], fin, tmp);
            #pragma unroll
            for (int j = 0; j < 8; ++j) fin[j] = tmp[j];
            r += wr[w];
        }
        const double p00r = fin[0], p00i = fin[1];
        // tr(CNOT^H U) = 2*P00; fidelity = |2*P00|^2 / 16.
        const double tr_re = 2.0 * p00r, tr_im = 2.0 * p00i;
        const double fid = (tr_re * tr_re + tr_im * tr_im) / 16.0;
        const double reg_mean = r / (3.0 * (double)(N_STEPS - 1));
        const double total = (1.0 - fid) + 0.01 * reg_mean;
        out[0] = (float)total;
        out[1] = (float)fid;
    }
}

extern "C" void kernel_launch(void* const* d_in, const int* in_sizes, int n_in,
                              void* d_out, int out_size, void* d_ws, size_t ws_size,
                              hipStream_t stream) {
    const float* pulses = (const float*)d_in[0];
    const float* dt_ptr = (const float*)d_in[1];
    float* out = (float*)d_out;
    double* ws = (double*)d_ws;

    lindblad_partial_kernel<<<K1_BLOCKS, K1_THREADS, 0, stream>>>(pulses, dt_ptr, ws);
    lindblad_final_kernel<<<1, K2_THREADS, 0, stream>>>(ws, out);
}